// Round 2
// baseline (2116.414 us; speedup 1.0000x reference)
//
#include <hip/hip_runtime.h>
#include <hip/hip_bf16.h>

// MoEReadout round 2: top-2 PAIR bucketing (15 combos) + 32-atom tiles for
// 3 blocks/CU occupancy.
//
// Pipeline:
//  k_cvt_w1/w2 : fp32 -> bf16 weights into ws (6.3 MB)
//  k_fill      : zero counts/cursors, idxl=-1, tile_pair=-1
//  k_router    : per-atom softmax top-2 -> pair id (C(6,2)=15) + both gates
//  k_scan      : 1-block exclusive scan of padded (x32) pair counts + tile_pair
//  k_scatter   : atom -> slot within its pair bucket
//  k_moe       : per 32-atom pair-homogeneous tile: stage X once, run
//                {a, b, shared0, shared1}; H chunked (256 cols) through small
//                LDS buffer; persistent 32x256 OUT accumulators; Y written once.

typedef __attribute__((ext_vector_type(8))) short short8;   // 8 x bf16
typedef __attribute__((ext_vector_type(4))) float f32x4;    // MFMA acc

#define IN_F 512
#define HID  512
#define OUT_F 256
#define TILE 32

__device__ inline unsigned short f2bf(float f) {
    __hip_bfloat16 h = __float2bfloat16(f);
    return *reinterpret_cast<unsigned short*>(&h);
}

// ---------- weight conversion ----------
__global__ void k_cvt_w1(const float* __restrict__ rW1, const float* __restrict__ sW1,
                         unsigned short* __restrict__ dst) {
    int i = blockIdx.x * 256 + threadIdx.x;          // < 8*512*512
    int e = i >> 18;
    int off = i & ((1 << 18) - 1);
    float v = (e < 6) ? rW1[(size_t)e * 262144 + off]
                      : sW1[(size_t)(e - 6) * 262144 + off];
    dst[i] = f2bf(v);
}

__global__ void k_cvt_w2(const float* __restrict__ rW2, const float* __restrict__ sW2,
                         unsigned short* __restrict__ dst) {
    int i = blockIdx.x * 256 + threadIdx.x;          // < 8*256*512
    int e = i >> 17;
    int off = i & ((1 << 17) - 1);
    float v = (e < 6) ? rW2[(size_t)e * 131072 + off]
                      : sW2[(size_t)(e - 6) * 131072 + off];
    dst[i] = f2bf(v);
}

// ---------- bucket state init ----------
__global__ void k_fill(int* __restrict__ counts, int* __restrict__ cursors,
                       int* __restrict__ idxl, int* __restrict__ tile_pair,
                       int CAP, int TMAX) {
    int i = blockIdx.x * 256 + threadIdx.x;
    if (i < 16) { counts[i] = 0; cursors[i] = 0; }
    if (i < TMAX) tile_pair[i] = -1;
    if (i < CAP) idxl[i] = -1;
}

// ---------- router: top-2 -> pair id + gates ----------
__global__ void k_router(const int* __restrict__ species, const float* __restrict__ emb,
                         const float* __restrict__ Wr,
                         int* __restrict__ pid, float* __restrict__ gA, float* __restrict__ gB,
                         int* __restrict__ counts, int N) {
    int i = blockIdx.x * 256 + threadIdx.x;
    if (i >= N) return;
    int z = species[i];
    float u[16];
#pragma unroll
    for (int k = 0; k < 16; ++k) {
        float v = emb[z * 16 + k];
        u[k] = v / (1.f + __expf(-v));               // silu
    }
    float s[6];
    float mx = -1e30f;
#pragma unroll
    for (int e = 0; e < 6; ++e) {
        float a = 0.f;
#pragma unroll
        for (int k = 0; k < 16; ++k) a += u[k] * Wr[e * 16 + k];
        s[e] = a;
        mx = fmaxf(mx, a);
    }
    float sum = 0.f;
#pragma unroll
    for (int e = 0; e < 6; ++e) { s[e] = __expf(s[e] - mx); sum += s[e]; }
    float inv = 1.f / sum;
    int i0 = 0;
#pragma unroll
    for (int e = 1; e < 6; ++e) if (s[e] > s[i0]) i0 = e;
    int i1 = (i0 == 0) ? 1 : 0;
#pragma unroll
    for (int e = 0; e < 6; ++e) if (e != i0 && s[e] > s[i1]) i1 = e;
    float g0 = s[i0] * inv, g1 = s[i1] * inv;
    int a = min(i0, i1), b = max(i0, i1);
    float ga = (a == i0) ? g0 : g1;
    float gb = (a == i0) ? g1 : g0;
    const int PB[5] = {0, 5, 9, 12, 14};
    int p = PB[a] + (b - a - 1);
    pid[i] = p; gA[i] = ga; gB[i] = gb;
    atomicAdd(&counts[p], 1);
}

// ---------- scan: padded bucket offsets + tile->pair map ----------
__global__ void k_scan(const int* __restrict__ counts, int* __restrict__ offs,
                       int* __restrict__ tile_pair, int TMAX) {
    __shared__ int so[16];
    if (threadIdx.x == 0) {
        int acc = 0;
        for (int p = 0; p < 15; ++p) { so[p] = acc; acc += (counts[p] + 31) & ~31; }
        so[15] = acc;
        for (int p = 0; p < 16; ++p) offs[p] = so[p];
    }
    __syncthreads();
    for (int t = threadIdx.x; t < TMAX; t += blockDim.x) {
        int t32 = t * 32;
        if (t32 < so[15]) {
            int p = 0;
            while (!(t32 >= so[p] && t32 < so[p + 1])) ++p;
            tile_pair[t] = p;
        }
    }
}

// ---------- scatter atoms into pair buckets ----------
__global__ void k_scatter(const int* __restrict__ pid, const float* __restrict__ gA,
                          const float* __restrict__ gB, const int* __restrict__ offs,
                          int* __restrict__ cursors, int* __restrict__ idxl,
                          float* __restrict__ gAl, float* __restrict__ gBl, int N) {
    int i = blockIdx.x * 256 + threadIdx.x;
    if (i >= N) return;
    int p = pid[i];
    int pos = atomicAdd(&cursors[p], 1);
    int slot = offs[p] + pos;
    idxl[slot] = i; gAl[slot] = gA[i]; gBl[slot] = gB[i];
}

// ---------- fused MoE MLP over pair-homogeneous 32-atom tiles ----------
// LDS: xs 32x520 bf16 (33.3 KB) + hs 32x264 bf16 (16.9 KB) + gates/idx (0.4 KB)
// -> ~50.6 KB -> 3 blocks/CU. 4 waves; wave wv owns H cols [.. +64) per chunk
// and OUT cols [64wv, 64wv+64).
__global__ __launch_bounds__(256, 3) void k_moe(
    const float* __restrict__ X,
    const unsigned short* __restrict__ W1all,    // [8][512][512] bf16
    const unsigned short* __restrict__ W2all,    // [8][256][512] bf16
    const int* __restrict__ idxl, const float* __restrict__ gAl,
    const float* __restrict__ gBl, const int* __restrict__ tile_pair,
    const float* __restrict__ rb1, const float* __restrict__ rb2,
    const float* __restrict__ sb1, const float* __restrict__ sb2,
    float* __restrict__ Y)
{
    const int t = blockIdx.x;
    const int p = tile_pair[t];
    if (p < 0) return;
    // decode pair id -> (ea < eb)
    int ea = 0, eb = 1;
    {
        int pp = p;
#pragma unroll
        for (int a = 0; a < 5; ++a) {
            int span = 5 - a;
            if (pp < span) { ea = a; eb = a + 1 + pp; break; }
            pp -= span;
        }
    }

    __shared__ unsigned short xs[TILE][520];
    __shared__ unsigned short hs[TILE][264];
    __shared__ float gsA[TILE], gsB[TILE];
    __shared__ int idxs[TILE];

    const int tid = threadIdx.x;
    if (tid < TILE) {
        int slot = t * TILE + tid;
        int gi = idxl[slot];
        idxs[tid] = gi;
        gsA[tid] = (gi >= 0) ? gAl[slot] : 0.f;
        gsB[tid] = (gi >= 0) ? gBl[slot] : 0.f;
    }
    __syncthreads();

    // stage X tile (fp32 -> bf16), gathered rows; pad rows read row 0 (gated off)
    for (int i = tid; i < TILE * 128; i += 256) {
        int r = i >> 7, c4 = i & 127;
        int gi = idxs[r]; if (gi < 0) gi = 0;
        float4 v = reinterpret_cast<const float4*>(X + (size_t)gi * IN_F)[c4];
        ushort4 pk;
        pk.x = f2bf(v.x); pk.y = f2bf(v.y); pk.z = f2bf(v.z); pk.w = f2bf(v.w);
        *reinterpret_cast<ushort4*>(&xs[r][c4 * 4]) = pk;
    }
    __syncthreads();

    const int wv = tid >> 6;
    const int lane = tid & 63;
    const int quad = lane >> 4;
    const int l16 = lane & 15;

    f32x4 outacc[2][4] = {};   // 32 x 64 per wave, cols [64wv, 64wv+64)

    for (int ei = 0; ei < 4; ++ei) {
        const int ex = (ei == 0) ? ea : (ei == 1) ? eb : (ei + 4);  // 6,7 shared
        const unsigned short* W1 = W1all + (size_t)ex * (HID * IN_F);
        const unsigned short* W2 = W2all + (size_t)ex * (OUT_F * HID);
        const float* b1 = (ex < 6) ? rb1 + ex * HID   : sb1 + (ex - 6) * HID;
        const float* b2 = (ex < 6) ? rb2 + ex * OUT_F : sb2 + (ex - 6) * OUT_F;

        // per-lane row gates (8 rows this lane touches)
        float gr[8];
#pragma unroll
        for (int mt = 0; mt < 2; ++mt)
#pragma unroll
            for (int r = 0; r < 4; ++r) {
                int row = mt * 16 + quad * 4 + r;
                gr[mt * 4 + r] = (ei == 0) ? gsA[row] : (ei == 1) ? gsB[row] : 1.f;
            }

        for (int j = 0; j < 2; ++j) {              // H column chunks of 256
            const int hbase = j * 256 + wv * 64;   // this wave's H cols
            // ---- phase A: H' chunk = gate * silu(X @ W1^T + b1)
            f32x4 acc[2][4] = {};
            for (int kk = 0; kk < IN_F; kk += 32) {
                short8 af[2], bfr[4];
#pragma unroll
                for (int mt = 0; mt < 2; ++mt)
                    af[mt] = *reinterpret_cast<const short8*>(&xs[mt * 16 + l16][kk + quad * 8]);
#pragma unroll
                for (int nt = 0; nt < 4; ++nt)
                    bfr[nt] = *reinterpret_cast<const short8*>(
                        &W1[(size_t)(hbase + nt * 16 + l16) * IN_F + kk + quad * 8]);
#pragma unroll
                for (int mt = 0; mt < 2; ++mt)
#pragma unroll
                    for (int nt = 0; nt < 4; ++nt)
                        acc[mt][nt] = __builtin_amdgcn_mfma_f32_16x16x32_bf16(
                            af[mt], bfr[nt], acc[mt][nt], 0, 0, 0);
            }
#pragma unroll
            for (int mt = 0; mt < 2; ++mt)
#pragma unroll
                for (int nt = 0; nt < 4; ++nt) {
                    int hcol = wv * 64 + nt * 16 + l16;        // hs col
                    float bb = b1[hbase + nt * 16 + l16];
#pragma unroll
                    for (int r = 0; r < 4; ++r) {
                        int row = mt * 16 + quad * 4 + r;
                        float v = acc[mt][nt][r] + bb;
                        float h = v / (1.f + __expf(-v));
                        hs[row][hcol] = f2bf(h * gr[mt * 4 + r]);
                    }
                }
            __syncthreads();

            // ---- phase B: OUT += H'chunk @ W2^T (K=256)
            for (int kk = 0; kk < 256; kk += 32) {
                short8 af[2], bfr[4];
#pragma unroll
                for (int mt = 0; mt < 2; ++mt)
                    af[mt] = *reinterpret_cast<const short8*>(&hs[mt * 16 + l16][kk + quad * 8]);
#pragma unroll
                for (int nt = 0; nt < 4; ++nt)
                    bfr[nt] = *reinterpret_cast<const short8*>(
                        &W2[(size_t)(wv * 64 + nt * 16 + l16) * HID + j * 256 + kk + quad * 8]);
#pragma unroll
                for (int mt = 0; mt < 2; ++mt)
#pragma unroll
                    for (int nt = 0; nt < 4; ++nt)
                        outacc[mt][nt] = __builtin_amdgcn_mfma_f32_16x16x32_bf16(
                            af[mt], bfr[nt], outacc[mt][nt], 0, 0, 0);
            }
            __syncthreads();
        }

        // ---- + gate * b2
#pragma unroll
        for (int mt = 0; mt < 2; ++mt)
#pragma unroll
            for (int nt = 0; nt < 4; ++nt) {
                float bb = b2[wv * 64 + nt * 16 + l16];
#pragma unroll
                for (int r = 0; r < 4; ++r)
                    outacc[mt][nt][r] += gr[mt * 4 + r] * bb;
            }
    }

    // write Y (each atom lives in exactly one tile)
#pragma unroll
    for (int mt = 0; mt < 2; ++mt)
#pragma unroll
        for (int nt = 0; nt < 4; ++nt)
#pragma unroll
            for (int r = 0; r < 4; ++r) {
                int row = mt * 16 + quad * 4 + r;
                int gi = idxs[row];
                if (gi >= 0)
                    Y[(size_t)gi * OUT_F + wv * 64 + nt * 16 + l16] = outacc[mt][nt][r];
            }
}

extern "C" void kernel_launch(void* const* d_in, const int* in_sizes, int n_in,
                              void* d_out, int out_size, void* d_ws, size_t ws_size,
                              hipStream_t stream) {
    const float* X       = (const float*)d_in[0];
    const int*   species = (const int*)d_in[1];
    const float* emb     = (const float*)d_in[2];
    const float* Wr      = (const float*)d_in[3];
    const float* rW1     = (const float*)d_in[4];
    const float* rb1     = (const float*)d_in[5];
    const float* rW2     = (const float*)d_in[6];
    const float* rb2     = (const float*)d_in[7];
    const float* sW1     = (const float*)d_in[8];
    const float* sb1     = (const float*)d_in[9];
    const float* sW2     = (const float*)d_in[10];
    const float* sb2     = (const float*)d_in[11];
    float* Y = (float*)d_out;
    const int N = in_sizes[1];

    const int CAP  = N + 15 * 32;      // worst-case padded bucket total
    const int TMAX = CAP / 32;

    // workspace layout (256B aligned chunks)
    size_t o = 0;
    auto take = [&](size_t bytes) { size_t r = o; o += (bytes + 255) & ~(size_t)255; return r; };
    char* ws = (char*)d_ws;
    unsigned short* w1bf   = (unsigned short*)(ws + take((size_t)8 * HID * IN_F * 2));
    unsigned short* w2bf   = (unsigned short*)(ws + take((size_t)8 * OUT_F * HID * 2));
    int*   pid      = (int*)  (ws + take((size_t)N * 4));
    float* gA       = (float*)(ws + take((size_t)N * 4));
    float* gB       = (float*)(ws + take((size_t)N * 4));
    int*   counts   = (int*)  (ws + take(64));
    int*   cursors  = (int*)  (ws + take(64));
    int*   offs     = (int*)  (ws + take(64));
    int*   idxl     = (int*)  (ws + take((size_t)CAP * 4));
    float* gAl      = (float*)(ws + take((size_t)CAP * 4));
    float* gBl      = (float*)(ws + take((size_t)CAP * 4));
    int*   tile_pair= (int*)  (ws + take((size_t)TMAX * 4));

    k_cvt_w1<<<(8 * HID * IN_F) / 256, 256, 0, stream>>>(rW1, sW1, w1bf);
    k_cvt_w2<<<(8 * OUT_F * HID) / 256, 256, 0, stream>>>(rW2, sW2, w2bf);
    k_fill<<<(CAP + 255) / 256, 256, 0, stream>>>(counts, cursors, idxl, tile_pair, CAP, TMAX);
    k_router<<<(N + 255) / 256, 256, 0, stream>>>(species, emb, Wr, pid, gA, gB, counts, N);
    k_scan<<<1, 256, 0, stream>>>(counts, offs, tile_pair, TMAX);
    k_scatter<<<(N + 255) / 256, 256, 0, stream>>>(pid, gA, gB, offs, cursors, idxl, gAl, gBl, N);
    k_moe<<<TMAX, 256, 0, stream>>>(X, w1bf, w2bf, idxl, gAl, gBl, tile_pair,
                                    rb1, rb2, sb1, sb2, Y);
}

// Round 4
// 1476.053 us; speedup vs baseline: 1.4338x; 1.4338x over previous
//
#include <hip/hip_runtime.h>
#include <hip/hip_bf16.h>

// MoEReadout round 4 (= round 3 with compile fix): pair-bucketed (15 combos)
// 32-atom tiles.
//  - k_router/k_scatter: block-aggregated atomics (LDS histogram).
//  - k_moe: nontemporal X loads + Y stores (keep weights L2-resident),
//    ping-pong register prefetch of W fragments.
//  - fix: __builtin_nontemporal_load needs ext_vector_type, not float4.

typedef __attribute__((ext_vector_type(8))) short short8;   // 8 x bf16
typedef __attribute__((ext_vector_type(4))) float f32x4;    // MFMA acc / 16B load

#define IN_F 512
#define HID  512
#define OUT_F 256
#define TILE 32

__device__ inline unsigned short f2bf(float f) {
    __hip_bfloat16 h = __float2bfloat16(f);
    return *reinterpret_cast<unsigned short*>(&h);
}

// ---------- weight conversion ----------
__global__ void k_cvt_w1(const float* __restrict__ rW1, const float* __restrict__ sW1,
                         unsigned short* __restrict__ dst) {
    int i = blockIdx.x * 256 + threadIdx.x;          // < 8*512*512
    int e = i >> 18;
    int off = i & ((1 << 18) - 1);
    float v = (e < 6) ? rW1[(size_t)e * 262144 + off]
                      : sW1[(size_t)(e - 6) * 262144 + off];
    dst[i] = f2bf(v);
}

__global__ void k_cvt_w2(const float* __restrict__ rW2, const float* __restrict__ sW2,
                         unsigned short* __restrict__ dst) {
    int i = blockIdx.x * 256 + threadIdx.x;          // < 8*256*512
    int e = i >> 17;
    int off = i & ((1 << 17) - 1);
    float v = (e < 6) ? rW2[(size_t)e * 131072 + off]
                      : sW2[(size_t)(e - 6) * 131072 + off];
    dst[i] = f2bf(v);
}

// ---------- bucket state init ----------
__global__ void k_fill(int* __restrict__ counts, int* __restrict__ cursors,
                       int* __restrict__ idxl, int* __restrict__ tile_pair,
                       int CAP, int TMAX) {
    int i = blockIdx.x * 256 + threadIdx.x;
    if (i < 16) { counts[i] = 0; cursors[i] = 0; }
    if (i < TMAX) tile_pair[i] = -1;
    if (i < CAP) idxl[i] = -1;
}

// ---------- router: top-2 -> pair id + gates (block-aggregated histogram) ----------
__global__ void k_router(const int* __restrict__ species, const float* __restrict__ emb,
                         const float* __restrict__ Wr,
                         int* __restrict__ pid, float* __restrict__ gA, float* __restrict__ gB,
                         int* __restrict__ counts, int N) {
    __shared__ int lcnt[16];
    int tid = threadIdx.x;
    if (tid < 16) lcnt[tid] = 0;
    __syncthreads();
    int i = blockIdx.x * 256 + tid;
    if (i < N) {
        int z = species[i];
        float u[16];
#pragma unroll
        for (int k = 0; k < 16; ++k) {
            float v = emb[z * 16 + k];
            u[k] = v / (1.f + __expf(-v));               // silu
        }
        float s[6];
        float mx = -1e30f;
#pragma unroll
        for (int e = 0; e < 6; ++e) {
            float a = 0.f;
#pragma unroll
            for (int k = 0; k < 16; ++k) a += u[k] * Wr[e * 16 + k];
            s[e] = a;
            mx = fmaxf(mx, a);
        }
        float sum = 0.f;
#pragma unroll
        for (int e = 0; e < 6; ++e) { s[e] = __expf(s[e] - mx); sum += s[e]; }
        float inv = 1.f / sum;
        int i0 = 0;
#pragma unroll
        for (int e = 1; e < 6; ++e) if (s[e] > s[i0]) i0 = e;
        int i1 = (i0 == 0) ? 1 : 0;
#pragma unroll
        for (int e = 0; e < 6; ++e) if (e != i0 && s[e] > s[i1]) i1 = e;
        float g0 = s[i0] * inv, g1 = s[i1] * inv;
        int a = min(i0, i1), b = max(i0, i1);
        const int PB[5] = {0, 5, 9, 12, 14};
        int p = PB[a] + (b - a - 1);
        pid[i] = p;
        gA[i] = (a == i0) ? g0 : g1;
        gB[i] = (a == i0) ? g1 : g0;
        atomicAdd(&lcnt[p], 1);          // LDS atomic — cheap
    }
    __syncthreads();
    if (tid < 15 && lcnt[tid] > 0) atomicAdd(&counts[tid], lcnt[tid]);
}

// ---------- scan: padded bucket offsets + tile->pair map ----------
__global__ void k_scan(const int* __restrict__ counts, int* __restrict__ offs,
                       int* __restrict__ tile_pair, int TMAX) {
    __shared__ int so[16];
    if (threadIdx.x == 0) {
        int acc = 0;
        for (int p = 0; p < 15; ++p) { so[p] = acc; acc += (counts[p] + 31) & ~31; }
        so[15] = acc;
        for (int p = 0; p < 16; ++p) offs[p] = so[p];
    }
    __syncthreads();
    for (int t = threadIdx.x; t < TMAX; t += blockDim.x) {
        int t32 = t * 32;
        if (t32 < so[15]) {
            int p = 0;
            while (!(t32 >= so[p] && t32 < so[p + 1])) ++p;
            tile_pair[t] = p;
        }
    }
}

// ---------- scatter atoms into pair buckets (block-aggregated) ----------
__global__ void k_scatter(const int* __restrict__ pid, const float* __restrict__ gA,
                          const float* __restrict__ gB, const int* __restrict__ offs,
                          int* __restrict__ cursors, int* __restrict__ idxl,
                          float* __restrict__ gAl, float* __restrict__ gBl, int N) {
    __shared__ int lcnt[16], lbase[16];
    int tid = threadIdx.x;
    if (tid < 16) lcnt[tid] = 0;
    __syncthreads();
    int i = blockIdx.x * 256 + tid;
    int p = -1, rank = 0;
    if (i < N) { p = pid[i]; rank = atomicAdd(&lcnt[p], 1); }
    __syncthreads();
    if (tid < 15 && lcnt[tid] > 0) lbase[tid] = atomicAdd(&cursors[tid], lcnt[tid]);
    __syncthreads();
    if (i < N) {
        int slot = offs[p] + lbase[p] + rank;
        idxl[slot] = i; gAl[slot] = gA[i]; gBl[slot] = gB[i];
    }
}

// ---------- fused MoE MLP over pair-homogeneous 32-atom tiles ----------
// LDS ~50.6 KB -> 3 blocks/CU (12 waves). 4 waves; per H-chunk of 256 cols a
// wave owns 64 H cols; OUT cols [64wv, 64wv+64) persistent in registers.
__global__ __launch_bounds__(256, 3) void k_moe(
    const float* __restrict__ X,
    const unsigned short* __restrict__ W1all,    // [8][512][512] bf16
    const unsigned short* __restrict__ W2all,    // [8][256][512] bf16
    const int* __restrict__ idxl, const float* __restrict__ gAl,
    const float* __restrict__ gBl, const int* __restrict__ tile_pair,
    const float* __restrict__ rb1, const float* __restrict__ rb2,
    const float* __restrict__ sb1, const float* __restrict__ sb2,
    float* __restrict__ Y)
{
    const int t = blockIdx.x;
    const int p = tile_pair[t];
    if (p < 0) return;
    int ea = 0, eb = 1;
    {
        int pp = p;
#pragma unroll
        for (int a = 0; a < 5; ++a) {
            int span = 5 - a;
            if (pp < span) { ea = a; eb = a + 1 + pp; break; }
            pp -= span;
        }
    }

    __shared__ unsigned short xs[TILE][520];
    __shared__ unsigned short hs[TILE][264];
    __shared__ float gsA[TILE], gsB[TILE];
    __shared__ int idxs[TILE];

    const int tid = threadIdx.x;
    if (tid < TILE) {
        int slot = t * TILE + tid;
        int gi = idxl[slot];
        idxs[tid] = gi;
        gsA[tid] = (gi >= 0) ? gAl[slot] : 0.f;
        gsB[tid] = (gi >= 0) ? gBl[slot] : 0.f;
    }
    __syncthreads();

    // stage X tile (fp32 -> bf16), nontemporal (don't evict weights from L2)
    for (int i = tid; i < TILE * 128; i += 256) {
        int r = i >> 7, c4 = i & 127;
        int gi = idxs[r]; if (gi < 0) gi = 0;
        f32x4 v = __builtin_nontemporal_load(
            reinterpret_cast<const f32x4*>(X + (size_t)gi * IN_F) + c4);
        ushort4 pk;
        pk.x = f2bf(v.x); pk.y = f2bf(v.y); pk.z = f2bf(v.z); pk.w = f2bf(v.w);
        *reinterpret_cast<ushort4*>(&xs[r][c4 * 4]) = pk;
    }
    __syncthreads();

    const int wv = tid >> 6;
    const int lane = tid & 63;
    const int quad = lane >> 4;
    const int l16 = lane & 15;

    f32x4 outacc[2][4] = {};   // 32 x 64 per wave, cols [64wv, 64wv+64)

    for (int ei = 0; ei < 4; ++ei) {
        const int ex = (ei == 0) ? ea : (ei == 1) ? eb : (ei + 4);  // 6,7 shared
        const unsigned short* W1 = W1all + (size_t)ex * (HID * IN_F);
        const unsigned short* W2 = W2all + (size_t)ex * (OUT_F * HID);
        const float* b1 = (ex < 6) ? rb1 + ex * HID   : sb1 + (ex - 6) * HID;
        const float* b2 = (ex < 6) ? rb2 + ex * OUT_F : sb2 + (ex - 6) * OUT_F;

        float gr[8];
#pragma unroll
        for (int mt = 0; mt < 2; ++mt)
#pragma unroll
            for (int r = 0; r < 4; ++r) {
                int row = mt * 16 + quad * 4 + r;
                gr[mt * 4 + r] = (ei == 0) ? gsA[row] : (ei == 1) ? gsB[row] : 1.f;
            }

        // per-lane W2 row pointers (fixed for the whole expert)
        const unsigned short* w2row[4];
#pragma unroll
        for (int nt = 0; nt < 4; ++nt)
            w2row[nt] = W2 + (size_t)(wv * 64 + nt * 16 + l16) * HID + quad * 8;

        for (int j = 0; j < 2; ++j) {              // H column chunks of 256
            const int hbase = j * 256 + wv * 64;   // this wave's H cols
            // per-lane W1 row pointers for this chunk
            const unsigned short* w1row[4];
#pragma unroll
            for (int nt = 0; nt < 4; ++nt)
                w1row[nt] = W1 + (size_t)(hbase + nt * 16 + l16) * IN_F + quad * 8;

            // ---- phase A: H' chunk = gate * silu(X @ W1^T + b1)
            // ping-pong register prefetch: batch of 4 W loads in flight
            f32x4 acc[2][4] = {};
            short8 bp[4], bq[4], a0[2], a1[2];
#pragma unroll
            for (int nt = 0; nt < 4; ++nt)
                bp[nt] = *reinterpret_cast<const short8*>(w1row[nt]);
#pragma unroll
            for (int kk = 0; kk < IN_F; kk += 64) {
#pragma unroll
                for (int nt = 0; nt < 4; ++nt)
                    bq[nt] = *reinterpret_cast<const short8*>(w1row[nt] + kk + 32);
#pragma unroll
                for (int mt = 0; mt < 2; ++mt)
                    a0[mt] = *reinterpret_cast<const short8*>(&xs[mt * 16 + l16][kk + quad * 8]);
#pragma unroll
                for (int mt = 0; mt < 2; ++mt)
#pragma unroll
                    for (int nt = 0; nt < 4; ++nt)
                        acc[mt][nt] = __builtin_amdgcn_mfma_f32_16x16x32_bf16(
                            a0[mt], bp[nt], acc[mt][nt], 0, 0, 0);
                if (kk + 64 < IN_F) {
#pragma unroll
                    for (int nt = 0; nt < 4; ++nt)
                        bp[nt] = *reinterpret_cast<const short8*>(w1row[nt] + kk + 64);
                }
#pragma unroll
                for (int mt = 0; mt < 2; ++mt)
                    a1[mt] = *reinterpret_cast<const short8*>(&xs[mt * 16 + l16][kk + 32 + quad * 8]);
#pragma unroll
                for (int mt = 0; mt < 2; ++mt)
#pragma unroll
                    for (int nt = 0; nt < 4; ++nt)
                        acc[mt][nt] = __builtin_amdgcn_mfma_f32_16x16x32_bf16(
                            a1[mt], bq[nt], acc[mt][nt], 0, 0, 0);
            }
#pragma unroll
            for (int mt = 0; mt < 2; ++mt)
#pragma unroll
                for (int nt = 0; nt < 4; ++nt) {
                    int hcol = wv * 64 + nt * 16 + l16;        // hs col
                    float bb = b1[hbase + nt * 16 + l16];
#pragma unroll
                    for (int r = 0; r < 4; ++r) {
                        int row = mt * 16 + quad * 4 + r;
                        float v = acc[mt][nt][r] + bb;
                        float h = v / (1.f + __expf(-v));
                        hs[row][hcol] = f2bf(h * gr[mt * 4 + r]);
                    }
                }
            __syncthreads();

            // ---- phase B: OUT += H'chunk @ W2^T (K=256), same prefetch scheme
#pragma unroll
            for (int nt = 0; nt < 4; ++nt)
                bp[nt] = *reinterpret_cast<const short8*>(w2row[nt] + j * 256);
#pragma unroll
            for (int kk = 0; kk < 256; kk += 64) {
#pragma unroll
                for (int nt = 0; nt < 4; ++nt)
                    bq[nt] = *reinterpret_cast<const short8*>(w2row[nt] + j * 256 + kk + 32);
#pragma unroll
                for (int mt = 0; mt < 2; ++mt)
                    a0[mt] = *reinterpret_cast<const short8*>(&hs[mt * 16 + l16][kk + quad * 8]);
#pragma unroll
                for (int mt = 0; mt < 2; ++mt)
#pragma unroll
                    for (int nt = 0; nt < 4; ++nt)
                        outacc[mt][nt] = __builtin_amdgcn_mfma_f32_16x16x32_bf16(
                            a0[mt], bp[nt], outacc[mt][nt], 0, 0, 0);
                if (kk + 64 < 256) {
#pragma unroll
                    for (int nt = 0; nt < 4; ++nt)
                        bp[nt] = *reinterpret_cast<const short8*>(w2row[nt] + j * 256 + kk + 64);
                }
#pragma unroll
                for (int mt = 0; mt < 2; ++mt)
                    a1[mt] = *reinterpret_cast<const short8*>(&hs[mt * 16 + l16][kk + 32 + quad * 8]);
#pragma unroll
                for (int mt = 0; mt < 2; ++mt)
#pragma unroll
                    for (int nt = 0; nt < 4; ++nt)
                        outacc[mt][nt] = __builtin_amdgcn_mfma_f32_16x16x32_bf16(
                            a1[mt], bq[nt], outacc[mt][nt], 0, 0, 0);
            }
            __syncthreads();
        }

        // ---- + gate * b2
#pragma unroll
        for (int mt = 0; mt < 2; ++mt)
#pragma unroll
            for (int nt = 0; nt < 4; ++nt) {
                float bb = b2[wv * 64 + nt * 16 + l16];
#pragma unroll
                for (int r = 0; r < 4; ++r)
                    outacc[mt][nt][r] += gr[mt * 4 + r] * bb;
            }
    }

    // write Y nontemporal (write-once stream; keep L2 for weights)
#pragma unroll
    for (int mt = 0; mt < 2; ++mt)
#pragma unroll
        for (int nt = 0; nt < 4; ++nt)
#pragma unroll
            for (int r = 0; r < 4; ++r) {
                int row = mt * 16 + quad * 4 + r;
                int gi = idxs[row];
                if (gi >= 0)
                    __builtin_nontemporal_store(outacc[mt][nt][r],
                        Y + (size_t)gi * OUT_F + wv * 64 + nt * 16 + l16);
            }
}

extern "C" void kernel_launch(void* const* d_in, const int* in_sizes, int n_in,
                              void* d_out, int out_size, void* d_ws, size_t ws_size,
                              hipStream_t stream) {
    const float* X       = (const float*)d_in[0];
    const int*   species = (const int*)d_in[1];
    const float* emb     = (const float*)d_in[2];
    const float* Wr      = (const float*)d_in[3];
    const float* rW1     = (const float*)d_in[4];
    const float* rb1     = (const float*)d_in[5];
    const float* rW2     = (const float*)d_in[6];
    const float* rb2     = (const float*)d_in[7];
    const float* sW1     = (const float*)d_in[8];
    const float* sb1     = (const float*)d_in[9];
    const float* sW2     = (const float*)d_in[10];
    const float* sb2     = (const float*)d_in[11];
    float* Y = (float*)d_out;
    const int N = in_sizes[1];

    const int CAP  = N + 15 * 32;
    const int TMAX = CAP / 32;

    size_t o = 0;
    auto take = [&](size_t bytes) { size_t r = o; o += (bytes + 255) & ~(size_t)255; return r; };
    char* ws = (char*)d_ws;
    unsigned short* w1bf   = (unsigned short*)(ws + take((size_t)8 * HID * IN_F * 2));
    unsigned short* w2bf   = (unsigned short*)(ws + take((size_t)8 * OUT_F * HID * 2));
    int*   pid      = (int*)  (ws + take((size_t)N * 4));
    float* gA       = (float*)(ws + take((size_t)N * 4));
    float* gB       = (float*)(ws + take((size_t)N * 4));
    int*   counts   = (int*)  (ws + take(64));
    int*   cursors  = (int*)  (ws + take(64));
    int*   offs     = (int*)  (ws + take(64));
    int*   idxl     = (int*)  (ws + take((size_t)CAP * 4));
    float* gAl      = (float*)(ws + take((size_t)CAP * 4));
    float* gBl      = (float*)(ws + take((size_t)CAP * 4));
    int*   tile_pair= (int*)  (ws + take((size_t)TMAX * 4));

    k_cvt_w1<<<(8 * HID * IN_F) / 256, 256, 0, stream>>>(rW1, sW1, w1bf);
    k_cvt_w2<<<(8 * OUT_F * HID) / 256, 256, 0, stream>>>(rW2, sW2, w2bf);
    k_fill<<<(CAP + 255) / 256, 256, 0, stream>>>(counts, cursors, idxl, tile_pair, CAP, TMAX);
    k_router<<<(N + 255) / 256, 256, 0, stream>>>(species, emb, Wr, pid, gA, gB, counts, N);
    k_scan<<<1, 256, 0, stream>>>(counts, offs, tile_pair, TMAX);
    k_scatter<<<(N + 255) / 256, 256, 0, stream>>>(pid, gA, gB, offs, cursors, idxl, gAl, gBl, N);
    k_moe<<<TMAX, 256, 0, stream>>>(X, w1bf, w2bf, idxl, gAl, gBl, tile_pair,
                                    rb1, rb2, sb1, sb2, Y);
}